// Round 13
// baseline (41.265 us; speedup 1.0000x reference)
//
#include <hip/hip_runtime.h>

constexpr int N = 8192;
// MIN_DIST = RADIUS*2*scale = 1.0f;  TRI = N(N+1)/2, exact in f32
constexpr float TRI = 33558528.0f;

__device__ __forceinline__ float fsqrt(float v) { return __builtin_amdgcn_sqrtf(v); }

// ws layout: p4[N] (float4) | row_sd[N] | row_sm[N] | row_corr[N]

__global__ __launch_bounds__(256)
void pack_kernel(const float* __restrict__ x, const float* __restrict__ y,
                 const float* __restrict__ z, float4* __restrict__ p4) {
    const int i = blockIdx.x * 256 + threadIdx.x;
    p4[i] = make_float4(x[i], y[i], z[i], 0.f);
}

// 1536 blocks:
//  [0,1024):    pair tiles — rows {4b..4b+3} (top) + {N-4b-4..N-4b-1} (bot),
//               j >= i sweep on the packed stream (R7 structure, verbatim).
//  [1024,1536): masked-prefix-run correction, 512-j speculative rounds,
//               16 rows/block, 4 rows/wave, ping-pong preload.
__global__ __launch_bounds__(256, 4)
void main_kernel(const float4* __restrict__ p4,
                 float* __restrict__ row_sd, float* __restrict__ row_sm,
                 float* __restrict__ row_corr) {
    const int tid  = threadIdx.x;
    const int lane = tid & 63;
    const int wave = tid >> 6;

    if (blockIdx.x < 1024) {
        const int b       = blockIdx.x;
        const int topBase = 4 * b;            // 0..4092
        const int botBase = N - 4 * (b + 1);  // 8188..4096

        float xr[8], yr[8], zr[8];
#pragma unroll
        for (int r = 0; r < 4; ++r) {
            const float4 pt = p4[topBase + r];
            const float4 pb = p4[botBase + r];
            xr[r]     = pt.x; yr[r]     = pt.y; zr[r]     = pt.z;
            xr[4 + r] = pb.x; yr[4 + r] = pb.y; zr[4 + r] = pb.z;
        }
        float sd[8], sm[8];
#pragma unroll
        for (int r = 0; r < 8; ++r) { sd[r] = 0.f; sm[r] = 0.f; }

#pragma unroll
        for (int g = 0; g < 2; ++g) {
            const int base = g ? botBase : topBase;
            const int ro   = g * 4;

            // head chunk [base, base+256): predicated vs diagonal and N
            {
                const int    j  = base + tid;
                const int    jc = (j < N) ? j : (N - 1);
                const float4 p  = p4[jc];
#pragma unroll
                for (int r = 0; r < 4; ++r) {
                    const float dx = p.x - xr[ro + r], dy = p.y - yr[ro + r], dz = p.z - zr[ro + r];
                    const float d  = fsqrt(dx * dx + dy * dy + dz * dz);
                    if (j < N && tid >= r) { sd[ro + r] += d; sm[ro + r] += fminf(d, 1.f); }
                }
            }
            // full middle 256-chunks: predicate-free, preloaded
            int j0 = base + 256;
            if (j0 + 256 <= N) {
                float4 p = p4[j0 + tid];
                while (true) {
                    const float4 c    = p;
                    const bool   more = (j0 + 512 <= N);
                    if (more) p = p4[j0 + 256 + tid];
#pragma unroll
                    for (int r = 0; r < 4; ++r) {
                        const float dx = c.x - xr[ro + r], dy = c.y - yr[ro + r], dz = c.z - zr[ro + r];
                        const float d  = fsqrt(dx * dx + dy * dy + dz * dz);
                        sd[ro + r] += d; sm[ro + r] += fminf(d, 1.f);
                    }
                    j0 += 256;
                    if (!more) break;
                }
            }
            // tail partial chunk
            if (j0 < N) {
                const int j = j0 + tid;
                if (j < N) {
                    const float4 p = p4[j];
#pragma unroll
                    for (int r = 0; r < 4; ++r) {
                        const float dx = p.x - xr[ro + r], dy = p.y - yr[ro + r], dz = p.z - zr[ro + r];
                        const float d  = fsqrt(dx * dx + dy * dy + dz * dz);
                        sd[ro + r] += d; sm[ro + r] += fminf(d, 1.f);
                    }
                }
            }
        }

        __shared__ float lsd[4][8];
        __shared__ float lsm[4][8];
#pragma unroll
        for (int r = 0; r < 8; ++r) {
            float a = sd[r], c = sm[r];
#pragma unroll
            for (int off = 32; off; off >>= 1) {
                a += __shfl_down(a, off);
                c += __shfl_down(c, off);
            }
            if (lane == 0) { lsd[wave][r] = a; lsm[wave][r] = c; }
        }
        __syncthreads();
        if (tid < 8) {
            const float a = lsd[0][tid] + lsd[1][tid] + lsd[2][tid] + lsd[3][tid];
            const float c = lsm[0][tid] + lsm[1][tid] + lsm[2][tid] + lsm[3][tid];
            const int   i = (tid < 4) ? (topBase + tid) : (botBase + tid - 4);
            row_sd[i] = a;
            row_sm[i] = c;
        }
    } else {
        // corr: run [i,k), k = first j with d>1 (or N). 512-j rounds, 8 float4
        // per lane per round, ping-pong preload so every round's loads were
        // issued one full round (~300cy of compute) earlier.
        const int cb = blockIdx.x - 1024;   // 0..511
#pragma unroll
        for (int rr = 0; rr < 4; ++rr) {
            const int    i  = 16 * cb + 4 * wave + rr;
            const float4 pi = p4[i];
            float corr = 0.f;
            int   jb   = i;

            float4 A[8], B[8];
#pragma unroll
            for (int q = 0; q < 8; ++q)
                A[q] = p4[min(jb + q * 64 + lane, N - 1)];

            while (true) {
                // --- process A (round at jb), preload B (jb+512) ---
#pragma unroll
                for (int q = 0; q < 8; ++q)
                    B[q] = p4[min(jb + 512 + q * 64 + lane, N - 1)];
                {
                    float d[8];
                    unsigned long long bm[8];
#pragma unroll
                    for (int q = 0; q < 8; ++q) {
                        const float dx = A[q].x - pi.x, dy = A[q].y - pi.y, dz = A[q].z - pi.z;
                        d[q] = fsqrt(dx * dx + dy * dy + dz * dz);
                        bm[q] = __ballot((jb + q * 64 + lane >= N) || (d[q] > 1.f));
                    }
                    int stop = 512;
#pragma unroll
                    for (int q = 0; q < 8; ++q)
                        if (stop == 512 && bm[q]) stop = q * 64 + __builtin_ctzll(bm[q]);
#pragma unroll
                    for (int q = 0; q < 8; ++q)
                        if (q * 64 + lane < stop) corr += 1.f - d[q];
                    if (stop < 512) break;
                    jb += 512;
                }
                // --- process B (round at jb), preload A (jb+512) ---
#pragma unroll
                for (int q = 0; q < 8; ++q)
                    A[q] = p4[min(jb + 512 + q * 64 + lane, N - 1)];
                {
                    float d[8];
                    unsigned long long bm[8];
#pragma unroll
                    for (int q = 0; q < 8; ++q) {
                        const float dx = B[q].x - pi.x, dy = B[q].y - pi.y, dz = B[q].z - pi.z;
                        d[q] = fsqrt(dx * dx + dy * dy + dz * dz);
                        bm[q] = __ballot((jb + q * 64 + lane >= N) || (d[q] > 1.f));
                    }
                    int stop = 512;
#pragma unroll
                    for (int q = 0; q < 8; ++q)
                        if (stop == 512 && bm[q]) stop = q * 64 + __builtin_ctzll(bm[q]);
#pragma unroll
                    for (int q = 0; q < 8; ++q)
                        if (q * 64 + lane < stop) corr += 1.f - d[q];
                    if (stop < 512) break;
                    jb += 512;
                }
            }
#pragma unroll
            for (int off = 32; off; off >>= 1) corr += __shfl_down(corr, off);
            if (lane == 0) row_corr[i] = corr;
        }
    }
}

// Single block, deterministic: totals + O(N) terms + loss assembly.
//   A = sum row_sd, M = sum row_sm, C = sum row_corr
//   sum_dist = 2A;  sum_relu = 2*(TRI - M) - N;  intersect = sum_relu - C
__global__ __launch_bounds__(256)
void reduce_kernel(const float* __restrict__ y, const float* __restrict__ z,
                   const float* __restrict__ row_sd, const float* __restrict__ row_sm,
                   const float* __restrict__ row_corr, float* __restrict__ out) {
    const int tid = threadIdx.x;
    float A = 0.f, M = 0.f, C = 0.f, fix = 0.f, noise = 0.f;
    for (int i = tid; i < N; i += 256) {
        A += row_sd[i];
        M += row_sm[i];
        C += row_corr[i];
        const float yv = y[i], zv = z[i];
        fix += fmaxf(yv - 1.f, 0.f) + fmaxf(-1.f - yv, 0.f)
             + fmaxf(zv - 1.f, 0.f) + fmaxf(-1.f - zv, 0.f);
        if (i < N - 2) {
            const float d2y = y[i + 2] - 2.f * y[i + 1] + y[i];
            const float d2z = z[i + 2] - 2.f * z[i + 1] + z[i];
            noise += d2y * d2y + d2z * d2z;
        }
    }
    __shared__ float s[5][4];
    const int lane = tid & 63, wave = tid >> 6;
    float v[5] = {A, M, C, fix, noise};
#pragma unroll
    for (int c = 0; c < 5; ++c) {
#pragma unroll
        for (int off = 32; off; off >>= 1) v[c] += __shfl_down(v[c], off);
        if (lane == 0) s[c][wave] = v[c];
    }
    __syncthreads();
    if (tid == 0) {
        float t[5];
#pragma unroll
        for (int c = 0; c < 5; ++c) t[c] = s[c][0] + s[c][1] + s[c][2] + s[c][3];
        out[0] = t[3] + (2.f * t[0]) / 10000.f
               + (2.f * (TRI - t[1]) - (float)N - t[2]) + 10.f * t[4];
    }
}

extern "C" void kernel_launch(void* const* d_in, const int* in_sizes, int n_in,
                              void* d_out, int out_size, void* d_ws, size_t ws_size,
                              hipStream_t stream) {
    const float* x = (const float*)d_in[0];
    const float* y = (const float*)d_in[1];
    const float* z = (const float*)d_in[2];
    float* out      = (float*)d_out;
    float4* p4      = (float4*)d_ws;
    float* row_sd   = (float*)(p4 + N);
    float* row_sm   = row_sd + N;
    float* row_corr = row_sm + N;

    pack_kernel<<<N / 256, 256, 0, stream>>>(x, y, z, p4);
    main_kernel<<<1536, 256, 0, stream>>>(p4, row_sd, row_sm, row_corr);
    reduce_kernel<<<1, 256, 0, stream>>>(y, z, row_sd, row_sm, row_corr, out);
}